// Round 1
// baseline (798.609 us; speedup 1.0000x reference)
//
#include <hip/hip_runtime.h>
#include <hip/hip_bf16.h>

// Problem constants (B=2, S=2048 -> T=4096 tokens)
#define TOK  4096
#define DD   1024
#define FF   4096
#define EE   8
#define BM   128
#define BN   128
#define BK   64
#define ASTR 88            // LDS row stride in shorts: 176B = 11*16 (aligned), 2-way bank max
#define MPAD (TOK*2 + EE*BM)   // 9216 padded slots

typedef __attribute__((ext_vector_type(8))) short  short8;
typedef __attribute__((ext_vector_type(4))) float  f32x4;

__device__ inline unsigned short f2bf(float f) {
    __hip_bfloat16 h = __float2bfloat16(f);
    return __builtin_bit_cast(unsigned short, h);
}

// ---------------- x -> bf16 ----------------
__global__ __launch_bounds__(256) void cvt_x(const float* __restrict__ x,
                                             unsigned short* __restrict__ xb) {
    size_t i = ((size_t)blockIdx.x * 256 + threadIdx.x) * 4;
    float4 v = *(const float4*)(x + i);
    ushort4 o;
    o.x = f2bf(v.x); o.y = f2bf(v.y); o.z = f2bf(v.z); o.w = f2bf(v.w);
    *(ushort4*)(xb + i) = o;
}

// ---------------- gate: scores, top-2, softmax ----------------
__global__ __launch_bounds__(256) void gate_kernel(const float* __restrict__ x,
                                                   const float* __restrict__ Wg,
                                                   const float* __restrict__ bg,
                                                   int* __restrict__ tidx,
                                                   float* __restrict__ tp,
                                                   int* __restrict__ counts) {
    int token = blockIdx.x;
    int t = threadIdx.x;
    const float* xr = x + (size_t)token * DD;
    float acc[EE];
#pragma unroll
    for (int e = 0; e < EE; e++) acc[e] = 0.f;

    float4 xv = *(const float4*)(xr + t * 4);
    const float* wr = Wg + (size_t)(t * 4) * EE;   // [D][E], 4 consecutive rows
#pragma unroll
    for (int j = 0; j < 4; j++) {
        float xd = (j == 0) ? xv.x : (j == 1) ? xv.y : (j == 2) ? xv.z : xv.w;
        const float* wj = wr + j * EE;
#pragma unroll
        for (int e = 0; e < EE; e++) acc[e] += xd * wj[e];
    }
    // wave butterfly reduce
#pragma unroll
    for (int e = 0; e < EE; e++) {
        float v = acc[e];
#pragma unroll
        for (int off = 32; off >= 1; off >>= 1) v += __shfl_xor(v, off, 64);
        acc[e] = v;
    }
    __shared__ float sred[4][EE];
    int lane = t & 63, wv = t >> 6;
    if (lane == 0) {
#pragma unroll
        for (int e = 0; e < EE; e++) sred[wv][e] = acc[e];
    }
    __syncthreads();
    if (t == 0) {
        float s[EE];
#pragma unroll
        for (int e = 0; e < EE; e++)
            s[e] = sred[0][e] + sred[1][e] + sred[2][e] + sred[3][e] + bg[e];
        int i0 = 0;
#pragma unroll
        for (int e = 1; e < EE; e++) if (s[e] > s[i0]) i0 = e;
        int i1 = (i0 == 0) ? 1 : 0;
#pragma unroll
        for (int e = 0; e < EE; e++) if (e != i0 && s[e] > s[i1]) i1 = e;
        float e1 = expf(s[i1] - s[i0]);          // e0 = 1
        float inv = 1.f / (1.f + e1);
        tidx[token * 2]     = i0;
        tidx[token * 2 + 1] = i1;
        tp[token * 2]       = inv;
        tp[token * 2 + 1]   = e1 * inv;
        atomicAdd(&counts[i0], 1);
        atomicAdd(&counts[i1], 1);
    }
}

// ---------------- routing: padded prefix sum ----------------
__global__ void route_offsets(const int* __restrict__ counts,
                              int* __restrict__ offs, int* __restrict__ cursor) {
    if (threadIdx.x == 0) {
        int o = 0; offs[0] = 0;
        for (int e = 0; e < EE; e++) {
            cursor[e] = o;
            o += ((counts[e] + BM - 1) / BM) * BM;   // pad region to BM
            offs[e + 1] = o;
        }
    }
}

__global__ __launch_bounds__(256) void route_scatter(const int* __restrict__ tidx,
                                                     const float* __restrict__ tp,
                                                     int* __restrict__ cursor,
                                                     int* __restrict__ row_token,
                                                     float* __restrict__ row_prob) {
    int token = blockIdx.x * 256 + threadIdx.x;
    if (token >= TOK) return;
#pragma unroll
    for (int j = 0; j < 2; j++) {
        int e = tidx[token * 2 + j];
        int slot = atomicAdd(&cursor[e], 1);
        row_token[slot] = token;
        row_prob[slot]  = tp[token * 2 + j];
    }
}

// ---------------- transpose + fp32->bf16: src[R][C] -> dst[C][R] ----------------
__global__ __launch_bounds__(256) void transpose_cvt(const float* __restrict__ src,
                                                     unsigned short* __restrict__ dst,
                                                     int R, int C) {
    __shared__ float tile[64][68];
    int c0 = blockIdx.x * 64, r0 = blockIdx.y * 64;
    size_t slab = (size_t)blockIdx.z * R * C;
    src += slab; dst += slab;
    int t = threadIdx.x;
#pragma unroll
    for (int i = 0; i < 4; i++) {
        int r = i * 16 + (t >> 4);
        int c = (t & 15) * 4;
        float4 v = *(const float4*)(src + (size_t)(r0 + r) * C + c0 + c);
        tile[r][c] = v.x; tile[r][c + 1] = v.y; tile[r][c + 2] = v.z; tile[r][c + 3] = v.w;
    }
    __syncthreads();
#pragma unroll
    for (int i = 0; i < 4; i++) {
        int c = i * 16 + (t >> 4);
        int r = (t & 15) * 4;
        ushort4 o;
        o.x = f2bf(tile[r][c]);     o.y = f2bf(tile[r + 1][c]);
        o.z = f2bf(tile[r + 2][c]); o.w = f2bf(tile[r + 3][c]);
        *(ushort4*)(dst + (size_t)(c0 + c) * R + r0 + r) = o;
    }
}

// ---------------- GEMM1: H = relu(X[rows] @ W1t[e]^T + b1[e]) -> bf16 ----------------
__global__ __launch_bounds__(256) void ffn1(const unsigned short* __restrict__ xb,
                                            const unsigned short* __restrict__ w1t, // [E][F][D]
                                            const float* __restrict__ b1,           // [E][F]
                                            const int* __restrict__ offs,
                                            const int* __restrict__ row_token,
                                            unsigned short* __restrict__ Hb) {      // [MPAD][F]
    int n0 = blockIdx.x * BN, m0 = blockIdx.y * BM;
    int e = 0;
    while (e < EE && m0 >= offs[e + 1]) e++;
    if (e >= EE) return;

    __shared__ unsigned short As[BM * ASTR];
    __shared__ unsigned short Bs[BN * ASTR];
    int t = threadIdx.x, lane = t & 63, wv = t >> 6;
    int wm = (wv >> 1) * 64, wn = (wv & 1) * 64;
    f32x4 acc[4][4];
#pragma unroll
    for (int i = 0; i < 4; i++)
#pragma unroll
        for (int j = 0; j < 4; j++) acc[i][j] = (f32x4){0.f, 0.f, 0.f, 0.f};

    const unsigned short* wb = w1t + (size_t)e * FF * DD;
    int arow[4];
#pragma unroll
    for (int i = 0; i < 4; i++) {
        int tok = row_token[m0 + i * 32 + (t >> 3)];
        arow[i] = (tok < 0) ? 0 : tok;   // pad rows read dummy row 0 (finite, discarded later)
    }

    for (int kt = 0; kt < DD / BK; ++kt) {
        __syncthreads();
#pragma unroll
        for (int i = 0; i < 4; i++) {
            int r = i * 32 + (t >> 3);
            uint4 va = *(const uint4*)(xb + (size_t)arow[i] * DD + kt * BK + (t & 7) * 8);
            *(uint4*)(&As[r * ASTR + (t & 7) * 8]) = va;
            uint4 vb = *(const uint4*)(wb + (size_t)(n0 + r) * DD + kt * BK + (t & 7) * 8);
            *(uint4*)(&Bs[r * ASTR + (t & 7) * 8]) = vb;
        }
        __syncthreads();
#pragma unroll
        for (int kk = 0; kk < 2; kk++) {
            short8 af[4], bfm[4];
#pragma unroll
            for (int i = 0; i < 4; i++) {
                af[i]  = *(const short8*)(&As[(wm + i * 16 + (lane & 15)) * ASTR + kk * 32 + (lane >> 4) * 8]);
                bfm[i] = *(const short8*)(&Bs[(wn + i * 16 + (lane & 15)) * ASTR + kk * 32 + (lane >> 4) * 8]);
            }
#pragma unroll
            for (int i = 0; i < 4; i++)
#pragma unroll
                for (int j = 0; j < 4; j++)
                    acc[i][j] = __builtin_amdgcn_mfma_f32_16x16x32_bf16(af[i], bfm[j], acc[i][j], 0, 0, 0);
        }
    }
    const float* b1e = b1 + (size_t)e * FF;
#pragma unroll
    for (int j = 0; j < 4; j++) {
        int col = n0 + wn + j * 16 + (lane & 15);
        float bv = b1e[col];
#pragma unroll
        for (int i = 0; i < 4; i++) {
            int rb = m0 + wm + i * 16 + (lane >> 4) * 4;
#pragma unroll
            for (int r = 0; r < 4; r++) {
                float hv = fmaxf(acc[i][j][r] + bv, 0.f);
                Hb[(size_t)(rb + r) * FF + col] = f2bf(hv);
            }
        }
    }
}

// ---------------- GEMM2: out[tok] += prob * (H @ W2t[e]^T + b2[e]) ----------------
__global__ __launch_bounds__(256) void ffn2(const unsigned short* __restrict__ Hb,  // [MPAD][F]
                                            const unsigned short* __restrict__ w2t, // [E][D][F]
                                            const float* __restrict__ b2,           // [E][D]
                                            const int* __restrict__ offs,
                                            const int* __restrict__ row_token,
                                            const float* __restrict__ row_prob,
                                            float* __restrict__ out) {
    int n0 = blockIdx.x * BN, m0 = blockIdx.y * BM;
    int e = 0;
    while (e < EE && m0 >= offs[e + 1]) e++;
    if (e >= EE) return;

    __shared__ unsigned short As[BM * ASTR];
    __shared__ unsigned short Bs[BN * ASTR];
    int t = threadIdx.x, lane = t & 63, wv = t >> 6;
    int wm = (wv >> 1) * 64, wn = (wv & 1) * 64;
    f32x4 acc[4][4];
#pragma unroll
    for (int i = 0; i < 4; i++)
#pragma unroll
        for (int j = 0; j < 4; j++) acc[i][j] = (f32x4){0.f, 0.f, 0.f, 0.f};

    const unsigned short* wb = w2t + (size_t)e * DD * FF;

    for (int kt = 0; kt < FF / BK; ++kt) {
        __syncthreads();
#pragma unroll
        for (int i = 0; i < 4; i++) {
            int r = i * 32 + (t >> 3);
            uint4 va = *(const uint4*)(Hb + (size_t)(m0 + r) * FF + kt * BK + (t & 7) * 8);
            *(uint4*)(&As[r * ASTR + (t & 7) * 8]) = va;
            uint4 vb = *(const uint4*)(wb + (size_t)(n0 + r) * FF + kt * BK + (t & 7) * 8);
            *(uint4*)(&Bs[r * ASTR + (t & 7) * 8]) = vb;
        }
        __syncthreads();
#pragma unroll
        for (int kk = 0; kk < 2; kk++) {
            short8 af[4], bfm[4];
#pragma unroll
            for (int i = 0; i < 4; i++) {
                af[i]  = *(const short8*)(&As[(wm + i * 16 + (lane & 15)) * ASTR + kk * 32 + (lane >> 4) * 8]);
                bfm[i] = *(const short8*)(&Bs[(wn + i * 16 + (lane & 15)) * ASTR + kk * 32 + (lane >> 4) * 8]);
            }
#pragma unroll
            for (int i = 0; i < 4; i++)
#pragma unroll
                for (int j = 0; j < 4; j++)
                    acc[i][j] = __builtin_amdgcn_mfma_f32_16x16x32_bf16(af[i], bfm[j], acc[i][j], 0, 0, 0);
        }
    }
    const float* b2e = b2 + (size_t)e * DD;
#pragma unroll
    for (int i = 0; i < 4; i++) {
#pragma unroll
        for (int r = 0; r < 4; r++) {
            int slot = m0 + wm + i * 16 + (lane >> 4) * 4 + r;
            int tok = row_token[slot];
            if (tok < 0) continue;
            float p = row_prob[slot];
            float* orow = out + (size_t)tok * DD;
#pragma unroll
            for (int j = 0; j < 4; j++) {
                int col = n0 + wn + j * 16 + (lane & 15);
                atomicAdd(orow + col, p * (acc[i][j][r] + b2e[col]));
            }
        }
    }
}

extern "C" void kernel_launch(void* const* d_in, const int* in_sizes, int n_in,
                              void* d_out, int out_size, void* d_ws, size_t ws_size,
                              hipStream_t stream) {
    const float* x  = (const float*)d_in[0];
    const float* W1 = (const float*)d_in[1];
    const float* b1 = (const float*)d_in[2];
    const float* W2 = (const float*)d_in[3];
    const float* b2 = (const float*)d_in[4];
    const float* Wg = (const float*)d_in[5];
    const float* bg = (const float*)d_in[6];
    float* out = (float*)d_out;

    char* w = (char*)d_ws;
    unsigned short* xb   = (unsigned short*)w; w += (size_t)TOK * DD * 2;
    unsigned short* W1bt = (unsigned short*)w; w += (size_t)EE * FF * DD * 2;
    unsigned short* W2bt = (unsigned short*)w; w += (size_t)EE * DD * FF * 2;
    unsigned short* Hb   = (unsigned short*)w; w += (size_t)MPAD * FF * 2;
    int*   counts    = (int*)w;  w += 256;
    int*   offs      = (int*)w;  w += 256;
    int*   cursor    = (int*)w;  w += 256;
    int*   row_token = (int*)w;  w += (size_t)MPAD * 4;
    float* row_prob  = (float*)w; w += (size_t)MPAD * 4;
    int*   tidx      = (int*)w;  w += (size_t)TOK * 2 * 4;
    float* tp        = (float*)w; w += (size_t)TOK * 2 * 4;

    hipMemsetAsync(counts, 0, 256, stream);                       // counts = 0
    hipMemsetAsync(row_token, 0xFF, (size_t)MPAD * 4, stream);    // row_token = -1
    hipMemsetAsync(out, 0, (size_t)TOK * DD * 4, stream);         // out = 0

    cvt_x<<<(TOK * DD / 4) / 256, 256, 0, stream>>>(x, xb);
    gate_kernel<<<TOK, 256, 0, stream>>>(x, Wg, bg, tidx, tp, counts);
    route_offsets<<<1, 64, 0, stream>>>(counts, offs, cursor);
    route_scatter<<<TOK / 256, 256, 0, stream>>>(tidx, tp, cursor, row_token, row_prob);
    transpose_cvt<<<dim3(FF / 64, DD / 64, EE), 256, 0, stream>>>(W1, W1bt, DD, FF);
    transpose_cvt<<<dim3(DD / 64, FF / 64, EE), 256, 0, stream>>>(W2, W2bt, FF, DD);
    ffn1<<<dim3(FF / BN, MPAD / BM), 256, 0, stream>>>(xb, W1bt, b1, offs, row_token, Hb);
    ffn2<<<dim3(DD / BN, MPAD / BM), 256, 0, stream>>>(Hb, W2bt, b2, offs, row_token, row_prob, out);
}

// Round 2
// 728.872 us; speedup vs baseline: 1.0957x; 1.0957x over previous
//
#include <hip/hip_runtime.h>
#include <hip/hip_bf16.h>

// Problem constants (B=2, S=2048 -> T=4096 tokens)
#define TOK  4096
#define DD   1024
#define FF   4096
#define EE   8
#define BM   128
#define BN   128
#define BK   64
#define MPAD (TOK*2 + EE*BM)   // 9216 padded slots

typedef __attribute__((ext_vector_type(8))) short  short8;
typedef __attribute__((ext_vector_type(4))) float  f32x4;

__device__ inline unsigned short f2bf(float f) {
    __hip_bfloat16 h = __float2bfloat16(f);
    return __builtin_bit_cast(unsigned short, h);
}

// async global->LDS, 16B per lane; lds dest must be wave-uniform base (+lane*16 by HW)
__device__ inline void cp16(void* lds, const void* g) {
    __builtin_amdgcn_global_load_lds(
        (const __attribute__((address_space(1))) void*)g,
        (__attribute__((address_space(3))) void*)lds,
        16, 0, 0);
}

// ---------------- x -> bf16 ----------------
__global__ __launch_bounds__(256) void cvt_x(const float* __restrict__ x,
                                             unsigned short* __restrict__ xb) {
    size_t i = ((size_t)blockIdx.x * 256 + threadIdx.x) * 4;
    float4 v = *(const float4*)(x + i);
    ushort4 o;
    o.x = f2bf(v.x); o.y = f2bf(v.y); o.z = f2bf(v.z); o.w = f2bf(v.w);
    *(ushort4*)(xb + i) = o;
}

// ---------------- gate: scores, top-2, softmax ----------------
__global__ __launch_bounds__(256) void gate_kernel(const float* __restrict__ x,
                                                   const float* __restrict__ Wg,
                                                   const float* __restrict__ bg,
                                                   int* __restrict__ tidx,
                                                   float* __restrict__ tp,
                                                   int* __restrict__ counts) {
    int token = blockIdx.x;
    int t = threadIdx.x;
    const float* xr = x + (size_t)token * DD;
    float acc[EE];
#pragma unroll
    for (int e = 0; e < EE; e++) acc[e] = 0.f;

    float4 xv = *(const float4*)(xr + t * 4);
    const float* wr = Wg + (size_t)(t * 4) * EE;   // [D][E], 4 consecutive rows
#pragma unroll
    for (int j = 0; j < 4; j++) {
        float xd = (j == 0) ? xv.x : (j == 1) ? xv.y : (j == 2) ? xv.z : xv.w;
        const float* wj = wr + j * EE;
#pragma unroll
        for (int e = 0; e < EE; e++) acc[e] += xd * wj[e];
    }
#pragma unroll
    for (int e = 0; e < EE; e++) {
        float v = acc[e];
#pragma unroll
        for (int off = 32; off >= 1; off >>= 1) v += __shfl_xor(v, off, 64);
        acc[e] = v;
    }
    __shared__ float sred[4][EE];
    int lane = t & 63, wv = t >> 6;
    if (lane == 0) {
#pragma unroll
        for (int e = 0; e < EE; e++) sred[wv][e] = acc[e];
    }
    __syncthreads();
    if (t == 0) {
        float s[EE];
#pragma unroll
        for (int e = 0; e < EE; e++)
            s[e] = sred[0][e] + sred[1][e] + sred[2][e] + sred[3][e] + bg[e];
        int i0 = 0;
#pragma unroll
        for (int e = 1; e < EE; e++) if (s[e] > s[i0]) i0 = e;
        int i1 = (i0 == 0) ? 1 : 0;
#pragma unroll
        for (int e = 0; e < EE; e++) if (e != i0 && s[e] > s[i1]) i1 = e;
        float e1 = expf(s[i1] - s[i0]);          // e0 = 1
        float inv = 1.f / (1.f + e1);
        tidx[token * 2]     = i0;
        tidx[token * 2 + 1] = i1;
        tp[token * 2]       = inv;
        tp[token * 2 + 1]   = e1 * inv;
        atomicAdd(&counts[i0], 1);
        atomicAdd(&counts[i1], 1);
    }
}

// ---------------- routing: padded prefix sum ----------------
__global__ void route_offsets(const int* __restrict__ counts,
                              int* __restrict__ offs, int* __restrict__ cursor) {
    if (threadIdx.x == 0) {
        int o = 0; offs[0] = 0;
        for (int e = 0; e < EE; e++) {
            cursor[e] = o;
            o += ((counts[e] + BM - 1) / BM) * BM;   // pad region to BM
            offs[e + 1] = o;
        }
    }
}

__global__ __launch_bounds__(256) void route_scatter(const int* __restrict__ tidx,
                                                     const float* __restrict__ tp,
                                                     int* __restrict__ cursor,
                                                     int* __restrict__ row_token,
                                                     float* __restrict__ row_prob,
                                                     int* __restrict__ slot_of) {
    int token = blockIdx.x * 256 + threadIdx.x;
    if (token >= TOK) return;
#pragma unroll
    for (int j = 0; j < 2; j++) {
        int e = tidx[token * 2 + j];
        int slot = atomicAdd(&cursor[e], 1);
        row_token[slot] = token;
        row_prob[slot]  = tp[token * 2 + j];
        slot_of[token * 2 + j] = slot;
    }
}

// ---------------- transpose + fp32->bf16: src[R][C] -> dst[C][R] ----------------
__global__ __launch_bounds__(256) void transpose_cvt(const float* __restrict__ src,
                                                     unsigned short* __restrict__ dst,
                                                     int R, int C) {
    __shared__ float tile[64][65];
    int c0 = blockIdx.x * 64, r0 = blockIdx.y * 64;
    size_t slab = (size_t)blockIdx.z * R * C;
    src += slab; dst += slab;
    int t = threadIdx.x;
#pragma unroll
    for (int i = 0; i < 4; i++) {
        int r = i * 16 + (t >> 4);
        int c = (t & 15) * 4;
        float4 v = *(const float4*)(src + (size_t)(r0 + r) * C + c0 + c);
        tile[r][c] = v.x; tile[r][c + 1] = v.y; tile[r][c + 2] = v.z; tile[r][c + 3] = v.w;
    }
    __syncthreads();
#pragma unroll
    for (int i = 0; i < 4; i++) {
        int c = i * 16 + (t >> 4);
        int r = (t & 15) * 4;
        ushort4 o;
        o.x = f2bf(tile[r][c]);     o.y = f2bf(tile[r + 1][c]);
        o.z = f2bf(tile[r + 2][c]); o.w = f2bf(tile[r + 3][c]);
        *(ushort4*)(dst + (size_t)(c0 + c) * R + r0 + r) = o;
    }
}

// ---------------- GEMM1: H = relu(X[rows] @ W1t[e]^T + b1[e]) -> bf16 ----------------
// m97 structure: global_load_lds w16 staging into linear LDS, 2 barriers/K-step
__global__ __launch_bounds__(256) void ffn1(const unsigned short* __restrict__ xb,
                                            const unsigned short* __restrict__ w1t, // [E][F][D]
                                            const float* __restrict__ b1,           // [E][F]
                                            const int* __restrict__ offs,
                                            const int* __restrict__ row_token,
                                            unsigned short* __restrict__ Hb) {      // [MPAD][F]
    __shared__ unsigned short As[BM * BK];
    __shared__ unsigned short Bs[BN * BK];
    int bid = blockIdx.x, nwg = gridDim.x;          // nwg = 32*72, divisible by 8
    int swz = (bid & 7) * (nwg >> 3) + (bid >> 3);  // XCD-contiguous chunks
    int n0 = (swz % (FF / BN)) * BN;
    int m0 = (swz / (FF / BN)) * BM;
    int e = 0;
    while (e < EE && m0 >= offs[e + 1]) e++;
    if (e >= EE) return;

    int t = threadIdx.x, lane = t & 63, wv = t >> 6;
    int wm = (wv >> 1) * 64, wn = (wv & 1) * 64;

    const unsigned short* wb = w1t + (size_t)e * FF * DD;

    const unsigned short* gA[4];
    const unsigned short* gB[4];
#pragma unroll
    for (int i = 0; i < 4; i++) {
        int row = i * 32 + wv * 8 + (lane >> 3);
        int tok = row_token[m0 + row];
        if (tok < 0) tok = 0;                       // pad rows: dummy finite row
        gA[i] = xb + (size_t)tok * DD + (lane & 7) * 8;
        gB[i] = wb + (size_t)(n0 + row) * DD + (lane & 7) * 8;
    }

    f32x4 acc[4][4];
#pragma unroll
    for (int i = 0; i < 4; i++)
#pragma unroll
        for (int j = 0; j < 4; j++) acc[i][j] = (f32x4){0.f, 0.f, 0.f, 0.f};

    for (int kt = 0; kt < DD / BK; ++kt) {
#pragma unroll
        for (int i = 0; i < 4; i++) {
            cp16(&As[(i * 32 + wv * 8) * BK], gA[i] + kt * BK);
            cp16(&Bs[(i * 32 + wv * 8) * BK], gB[i] + kt * BK);
        }
        __syncthreads();                            // vmcnt(0) drain + barrier
#pragma unroll
        for (int kk = 0; kk < 2; kk++) {
            short8 af[4], bfm[4];
#pragma unroll
            for (int i = 0; i < 4; i++) {
                af[i]  = *(const short8*)(&As[(wm + i * 16 + (lane & 15)) * BK + kk * 32 + (lane >> 4) * 8]);
                bfm[i] = *(const short8*)(&Bs[(wn + i * 16 + (lane & 15)) * BK + kk * 32 + (lane >> 4) * 8]);
            }
#pragma unroll
            for (int i = 0; i < 4; i++)
#pragma unroll
                for (int j = 0; j < 4; j++)
                    acc[i][j] = __builtin_amdgcn_mfma_f32_16x16x32_bf16(af[i], bfm[j], acc[i][j], 0, 0, 0);
        }
        __syncthreads();                            // protect LDS before next stage
    }
    const float* b1e = b1 + (size_t)e * FF;
#pragma unroll
    for (int j = 0; j < 4; j++) {
        int col = n0 + wn + j * 16 + (lane & 15);
        float bv = b1e[col];
#pragma unroll
        for (int i = 0; i < 4; i++) {
            int rb = m0 + wm + i * 16 + (lane >> 4) * 4;
#pragma unroll
            for (int r = 0; r < 4; r++) {
                float hv = fmaxf(acc[i][j][r] + bv, 0.f);
                Hb[(size_t)(rb + r) * FF + col] = f2bf(hv);
            }
        }
    }
}

// ---------------- GEMM2: Y[slot] = H[slot] @ W2t[e]^T + b2[e] (fp32) ----------------
__global__ __launch_bounds__(256) void ffn2(const unsigned short* __restrict__ Hb,  // [MPAD][F]
                                            const unsigned short* __restrict__ w2t, // [E][D][F]
                                            const float* __restrict__ b2,           // [E][D]
                                            const int* __restrict__ offs,
                                            float* __restrict__ Y) {                // [MPAD][D]
    __shared__ unsigned short As[BM * BK];
    __shared__ unsigned short Bs[BN * BK];
    int bid = blockIdx.x, nwg = gridDim.x;          // nwg = 8*72, divisible by 8
    int swz = (bid & 7) * (nwg >> 3) + (bid >> 3);
    int n0 = (swz % (DD / BN)) * BN;
    int m0 = (swz / (DD / BN)) * BM;
    int e = 0;
    while (e < EE && m0 >= offs[e + 1]) e++;
    if (e >= EE) return;

    int t = threadIdx.x, lane = t & 63, wv = t >> 6;
    int wm = (wv >> 1) * 64, wn = (wv & 1) * 64;

    const unsigned short* wb = w2t + (size_t)e * DD * FF;

    const unsigned short* gA[4];
    const unsigned short* gB[4];
#pragma unroll
    for (int i = 0; i < 4; i++) {
        int row = i * 32 + wv * 8 + (lane >> 3);
        gA[i] = Hb + (size_t)(m0 + row) * FF + (lane & 7) * 8;
        gB[i] = wb + (size_t)(n0 + row) * FF + (lane & 7) * 8;
    }

    f32x4 acc[4][4];
#pragma unroll
    for (int i = 0; i < 4; i++)
#pragma unroll
        for (int j = 0; j < 4; j++) acc[i][j] = (f32x4){0.f, 0.f, 0.f, 0.f};

    for (int kt = 0; kt < FF / BK; ++kt) {
#pragma unroll
        for (int i = 0; i < 4; i++) {
            cp16(&As[(i * 32 + wv * 8) * BK], gA[i] + kt * BK);
            cp16(&Bs[(i * 32 + wv * 8) * BK], gB[i] + kt * BK);
        }
        __syncthreads();
#pragma unroll
        for (int kk = 0; kk < 2; kk++) {
            short8 af[4], bfm[4];
#pragma unroll
            for (int i = 0; i < 4; i++) {
                af[i]  = *(const short8*)(&As[(wm + i * 16 + (lane & 15)) * BK + kk * 32 + (lane >> 4) * 8]);
                bfm[i] = *(const short8*)(&Bs[(wn + i * 16 + (lane & 15)) * BK + kk * 32 + (lane >> 4) * 8]);
            }
#pragma unroll
            for (int i = 0; i < 4; i++)
#pragma unroll
                for (int j = 0; j < 4; j++)
                    acc[i][j] = __builtin_amdgcn_mfma_f32_16x16x32_bf16(af[i], bfm[j], acc[i][j], 0, 0, 0);
        }
        __syncthreads();
    }
    const float* b2e = b2 + (size_t)e * DD;
#pragma unroll
    for (int i = 0; i < 4; i++) {
#pragma unroll
        for (int r = 0; r < 4; r++) {
            int slot = m0 + wm + i * 16 + (lane >> 4) * 4 + r;
            float* yrow = Y + (size_t)slot * DD;
#pragma unroll
            for (int j = 0; j < 4; j++) {
                int col = n0 + wn + j * 16 + (lane & 15);
                yrow[col] = acc[i][j][r] + b2e[col];
            }
        }
    }
}

// ---------------- combine: out[t] = p0*Y[s0] + p1*Y[s1] ----------------
__global__ __launch_bounds__(256) void combine(const float* __restrict__ Y,
                                               const float* __restrict__ tp,
                                               const int* __restrict__ slot_of,
                                               float* __restrict__ out) {
    int tkn = blockIdx.x;
    int c = threadIdx.x * 4;
    int s0 = slot_of[tkn * 2], s1 = slot_of[tkn * 2 + 1];
    float p0 = tp[tkn * 2],    p1 = tp[tkn * 2 + 1];
    float4 y0 = *(const float4*)(Y + (size_t)s0 * DD + c);
    float4 y1 = *(const float4*)(Y + (size_t)s1 * DD + c);
    float4 o;
    o.x = p0 * y0.x + p1 * y1.x;
    o.y = p0 * y0.y + p1 * y1.y;
    o.z = p0 * y0.z + p1 * y1.z;
    o.w = p0 * y0.w + p1 * y1.w;
    *(float4*)(out + (size_t)tkn * DD + c) = o;
}

extern "C" void kernel_launch(void* const* d_in, const int* in_sizes, int n_in,
                              void* d_out, int out_size, void* d_ws, size_t ws_size,
                              hipStream_t stream) {
    const float* x  = (const float*)d_in[0];
    const float* W1 = (const float*)d_in[1];
    const float* b1 = (const float*)d_in[2];
    const float* W2 = (const float*)d_in[3];
    const float* b2 = (const float*)d_in[4];
    const float* Wg = (const float*)d_in[5];
    const float* bg = (const float*)d_in[6];
    float* out = (float*)d_out;

    char* w = (char*)d_ws;
    unsigned short* xb   = (unsigned short*)w; w += (size_t)TOK * DD * 2;
    unsigned short* W1bt = (unsigned short*)w; w += (size_t)EE * FF * DD * 2;
    unsigned short* W2bt = (unsigned short*)w; w += (size_t)EE * DD * FF * 2;
    unsigned short* Hb   = (unsigned short*)w; w += (size_t)MPAD * FF * 2;
    int*   counts    = (int*)w;  w += 256;
    int*   offs      = (int*)w;  w += 256;
    int*   cursor    = (int*)w;  w += 256;
    int*   row_token = (int*)w;  w += (size_t)MPAD * 4;
    float* row_prob  = (float*)w; w += (size_t)MPAD * 4;
    int*   tidx      = (int*)w;  w += (size_t)TOK * 2 * 4;
    float* tp        = (float*)w; w += (size_t)TOK * 2 * 4;
    int*   slot_of   = (int*)w;  w += (size_t)TOK * 2 * 4;
    // Y aliases W1bt's region: W1bt is dead after ffn1, Y (37.75MB) < 64MB region
    float* Y = (float*)W1bt;

    hipMemsetAsync(counts, 0, 256, stream);                       // counts = 0
    hipMemsetAsync(row_token, 0xFF, (size_t)MPAD * 4, stream);    // row_token = -1

    cvt_x<<<(TOK * DD / 4) / 256, 256, 0, stream>>>(x, xb);
    gate_kernel<<<TOK, 256, 0, stream>>>(x, Wg, bg, tidx, tp, counts);
    route_offsets<<<1, 64, 0, stream>>>(counts, offs, cursor);
    route_scatter<<<TOK / 256, 256, 0, stream>>>(tidx, tp, cursor, row_token, row_prob, slot_of);
    transpose_cvt<<<dim3(FF / 64, DD / 64, EE), 256, 0, stream>>>(W1, W1bt, DD, FF);
    transpose_cvt<<<dim3(DD / 64, FF / 64, EE), 256, 0, stream>>>(W2, W2bt, FF, DD);
    ffn1<<<(FF / BN) * (MPAD / BM), 256, 0, stream>>>(xb, W1bt, b1, offs, row_token, Hb);
    ffn2<<<(DD / BN) * (MPAD / BM), 256, 0, stream>>>(Hb, W2bt, b2, offs, Y);
    combine<<<TOK, 256, 0, stream>>>(Y, tp, slot_of, out);
}